// Round 1
// baseline (348.464 us; speedup 1.0000x reference)
//
#include <hip/hip_runtime.h>
#include <hip/hip_bf16.h>
#include <math.h>

#define T_SEQ 2048
#define NH 16
#define KVH 4
#define HD 128
#define DM 2048
#define KVD 512

typedef short bf16x8 __attribute__((ext_vector_type(8)));
typedef float f32x4 __attribute__((ext_vector_type(4)));

static __device__ __forceinline__ unsigned short f2bf(float f) {
    unsigned int x = __float_as_uint(f);
    x += 0x7fff + ((x >> 16) & 1);   // round-to-nearest-even
    return (unsigned short)(x >> 16);
}

static __device__ __forceinline__ f32x4 mfma16(bf16x8 a, bf16x8 b, f32x4 c) {
    return __builtin_amdgcn_mfma_f32_16x16x32_bf16(a, b, c, 0, 0, 0);
}

// ---------------- kernel 1: RoPE cos/sin table [T][64] ----------------
__global__ void rope_tab(const int* __restrict__ pos_ids,
                         float* __restrict__ cosT, float* __restrict__ sinT) {
    int t = blockIdx.x;
    int i = threadIdx.x;  // 0..63
    float pos = (float)pos_ids[t];
    float inv = powf(10000.0f, -(float)i * (1.0f / 64.0f));
    float a = pos * inv;
    cosT[t * 64 + i] = cosf(a);
    sinT[t * 64 + i] = sinf(a);
}

// ---------------- kernel 2: RMSNorm + RoPE for q,k -> bf16 head-major ----------------
__global__ __launch_bounds__(256) void qk_prep(
    const float* __restrict__ q, const float* __restrict__ k,
    const float* __restrict__ qw, const float* __restrict__ kw,
    const float* __restrict__ cosT, const float* __restrict__ sinT,
    unsigned short* __restrict__ Qb, unsigned short* __restrict__ Kb) {
    __shared__ float qr[DM];
    __shared__ float kr[KVD];
    __shared__ float redq[4], redk[4];
    int t = blockIdx.x, tid = threadIdx.x;

    // load q row (8 f32/thread) and k row (2 f32/thread), sum squares
    float qs = 0.f, ks = 0.f;
    {
        const float* qp = q + (size_t)t * DM + tid * 8;
        float4 v0 = *(const float4*)(qp);
        float4 v1 = *(const float4*)(qp + 4);
        float* dst = qr + tid * 8;
        dst[0] = v0.x; dst[1] = v0.y; dst[2] = v0.z; dst[3] = v0.w;
        dst[4] = v1.x; dst[5] = v1.y; dst[6] = v1.z; dst[7] = v1.w;
        qs = v0.x * v0.x + v0.y * v0.y + v0.z * v0.z + v0.w * v0.w +
             v1.x * v1.x + v1.y * v1.y + v1.z * v1.z + v1.w * v1.w;
        float2 kv = *(const float2*)(k + (size_t)t * KVD + tid * 2);
        kr[tid * 2] = kv.x; kr[tid * 2 + 1] = kv.y;
        ks = kv.x * kv.x + kv.y * kv.y;
    }
    for (int off = 32; off; off >>= 1) {
        qs += __shfl_down(qs, off);
        ks += __shfl_down(ks, off);
    }
    if ((tid & 63) == 0) { redq[tid >> 6] = qs; redk[tid >> 6] = ks; }
    __syncthreads();
    float qinv = rsqrtf((redq[0] + redq[1] + redq[2] + redq[3]) * (1.0f / DM) + 1e-5f);
    float kinv = rsqrtf((redk[0] + redk[1] + redk[2] + redk[3]) * (1.0f / KVD) + 1e-5f);

    // q: 8 elems per thread, same head, same rope half
    {
        int base = tid * 8;
        int h = base >> 7;
        int d = base & 127;
        bool lo = d < 64;
        int i0 = d & 63;
        int pb = lo ? base + 64 : base - 64;
        #pragma unroll
        for (int j = 0; j < 8; ++j) {
            float xv = qr[base + j] * qinv * qw[base + j];
            float pv = qr[pb + j] * qinv * qw[pb + j];
            float c = cosT[t * 64 + i0 + j];
            float s = sinT[t * 64 + i0 + j];
            float o = lo ? (xv * c - pv * s) : (xv * c + pv * s);
            Qb[((size_t)h * T_SEQ + t) * HD + d + j] = f2bf(o);
        }
    }
    // k: 2 elems per thread
    {
        int base = tid * 2;
        int h = base >> 7;
        int d = base & 127;
        bool lo = d < 64;
        int i0 = d & 63;
        int pb = lo ? base + 64 : base - 64;
        #pragma unroll
        for (int j = 0; j < 2; ++j) {
            float xv = kr[base + j] * kinv * kw[base + j];
            float pv = kr[pb + j] * kinv * kw[pb + j];
            float c = cosT[t * 64 + i0 + j];
            float s = sinT[t * 64 + i0 + j];
            float o = lo ? (xv * c - pv * s) : (xv * c + pv * s);
            Kb[((size_t)h * T_SEQ + t) * HD + d + j] = f2bf(o);
        }
    }
}

// ---------------- kernel 3: V -> bf16 transposed [KVH][128][T] ----------------
__global__ __launch_bounds__(256) void v_prep(const float* __restrict__ v,
                                              unsigned short* __restrict__ Vt) {
    __shared__ unsigned short tile[64][72];
    int tb = blockIdx.x;  // 32 t-tiles
    int cb = blockIdx.y;  // 8 c-tiles (over 512 cols)
    int tid = threadIdx.x;
    #pragma unroll 4
    for (int rep = 0; rep < 16; ++rep) {
        int e = rep * 256 + tid;
        int r = e >> 6;   // t within tile
        int c = e & 63;   // col within tile
        tile[c][r] = f2bf(v[(size_t)(tb * 64 + r) * KVD + cb * 64 + c]);
    }
    __syncthreads();
    #pragma unroll 4
    for (int rep = 0; rep < 16; ++rep) {
        int e = rep * 256 + tid;
        int cc = e >> 6;
        int tt = e & 63;
        Vt[(size_t)(cb * 64 + cc) * T_SEQ + tb * 64 + tt] = tile[cc][tt];
    }
}

// ---------------- kernel 4: w_out f32 -> bf16 ----------------
__global__ __launch_bounds__(256) void w_prep(const float* __restrict__ w,
                                              unsigned short* __restrict__ Wb) {
    size_t idx = ((size_t)blockIdx.x * 256 + threadIdx.x) * 4;
    float4 f = *(const float4*)(w + idx);
    ushort4 o;
    o.x = f2bf(f.x); o.y = f2bf(f.y); o.z = f2bf(f.z); o.w = f2bf(f.w);
    *(ushort4*)(Wb + idx) = o;
}

// ---------------- kernel 5: flash attention ----------------
// grid (T/64, NH), block 256 (4 waves, each 16 q-rows), K-tile = 32
__global__ __launch_bounds__(256) void attn_fwd(
    const unsigned short* __restrict__ Qb, const unsigned short* __restrict__ Kb,
    const unsigned short* __restrict__ Vt, unsigned short* __restrict__ Xo) {
    int qb = blockIdx.x;
    int h = blockIdx.y;
    int kh = h >> 2;  // GQA: 4 q heads per kv head
    int tid = threadIdx.x;
    int w = tid >> 6, l = tid & 63;
    int lr = l & 15, lg = l >> 4;
    int q0 = qb * 64 + w * 16;

    const unsigned short* Qh = Qb + (size_t)h * T_SEQ * HD;
    const unsigned short* Kh = Kb + (size_t)kh * T_SEQ * HD;
    const unsigned short* Vh = Vt + (size_t)kh * HD * T_SEQ;

    bf16x8 qf[4];
    #pragma unroll
    for (int ks = 0; ks < 4; ++ks)
        qf[ks] = *(const bf16x8*)(Qh + (size_t)(q0 + lr) * HD + ks * 32 + lg * 8);

    f32x4 acc[8];
    #pragma unroll
    for (int i = 0; i < 8; ++i) acc[i] = (f32x4){0.f, 0.f, 0.f, 0.f};
    float m[4] = {-1e30f, -1e30f, -1e30f, -1e30f};
    float sden[4] = {0.f, 0.f, 0.f, 0.f};

    __shared__ unsigned short P[4][16][40];  // padded: 2-way bank conflicts only

    const float scale = 0.08838834764831845f;  // 1/sqrt(128)
    int nkt = qb * 2 + 2;
    for (int kt = 0; kt < nkt; ++kt) {
        int kbase = kt * 32;
        // K fragments (B operand): rows kbase+lr / kbase+16+lr
        f32x4 s0 = {0.f, 0.f, 0.f, 0.f}, s1 = {0.f, 0.f, 0.f, 0.f};
        #pragma unroll
        for (int ks = 0; ks < 4; ++ks) {
            bf16x8 kf0 = *(const bf16x8*)(Kh + (size_t)(kbase + lr) * HD + ks * 32 + lg * 8);
            bf16x8 kf1 = *(const bf16x8*)(Kh + (size_t)(kbase + 16 + lr) * HD + ks * 32 + lg * 8);
            s0 = mfma16(qf[ks], kf0, s0);
            s1 = mfma16(qf[ks], kf1, s1);
        }
        // scale + causal mask (reference uses -10000 post-scale)
        float sc0[4], sc1[4], tm[4];
        int c0 = kbase + lr, c1 = kbase + 16 + lr;
        #pragma unroll
        for (int r = 0; r < 4; ++r) {
            int row = q0 + lg * 4 + r;
            sc0[r] = (c0 <= row) ? s0[r] * scale : -10000.0f;
            sc1[r] = (c1 <= row) ? s1[r] * scale : -10000.0f;
            tm[r] = fmaxf(sc0[r], sc1[r]);
        }
        // row-max over the 16 lanes of each group
        #pragma unroll
        for (int off = 1; off < 16; off <<= 1) {
            #pragma unroll
            for (int r = 0; r < 4; ++r) tm[r] = fmaxf(tm[r], __shfl_xor(tm[r], off));
        }
        float al[4], p0[4], p1[4], ts[4];
        #pragma unroll
        for (int r = 0; r < 4; ++r) {
            float mn = fmaxf(m[r], tm[r]);
            al[r] = __expf(m[r] - mn);
            m[r] = mn;
            p0[r] = __expf(sc0[r] - mn);
            p1[r] = __expf(sc1[r] - mn);
            ts[r] = p0[r] + p1[r];
        }
        #pragma unroll
        for (int off = 1; off < 16; off <<= 1) {
            #pragma unroll
            for (int r = 0; r < 4; ++r) ts[r] += __shfl_xor(ts[r], off);
        }
        #pragma unroll
        for (int r = 0; r < 4; ++r) sden[r] = sden[r] * al[r] + ts[r];
        #pragma unroll
        for (int i = 0; i < 8; ++i) {
            #pragma unroll
            for (int r = 0; r < 4; ++r) acc[i][r] *= al[r];
        }
        // P -> LDS (bf16), then read back in A-fragment layout
        __syncthreads();
        #pragma unroll
        for (int r = 0; r < 4; ++r) {
            P[w][lg * 4 + r][lr] = f2bf(p0[r]);
            P[w][lg * 4 + r][16 + lr] = f2bf(p1[r]);
        }
        __syncthreads();
        bf16x8 pa = *(const bf16x8*)(&P[w][lr][lg * 8]);
        #pragma unroll
        for (int d0 = 0; d0 < 8; ++d0) {
            bf16x8 vb = *(const bf16x8*)(Vh + (size_t)(d0 * 16 + lr) * T_SEQ + kbase + lg * 8);
            acc[d0] = mfma16(pa, vb, acc[d0]);
        }
    }
    // epilogue: normalize + write bf16 token-major [T][DM]
    float inv[4];
    #pragma unroll
    for (int r = 0; r < 4; ++r) inv[r] = 1.0f / sden[r];
    #pragma unroll
    for (int d0 = 0; d0 < 8; ++d0) {
        #pragma unroll
        for (int r = 0; r < 4; ++r) {
            int row = q0 + lg * 4 + r;
            Xo[(size_t)row * DM + h * HD + d0 * 16 + lr] = f2bf(acc[d0][r] * inv[r]);
        }
    }
}

// ---------------- kernel 6: out = X(bf16) @ W^T(bf16) -> f32 ----------------
// 128x128 tile, 4 waves (2x2), each wave 64x64 = 4x4 MFMA frags, K-step 32
__global__ __launch_bounds__(256) void outproj(
    const unsigned short* __restrict__ X, const unsigned short* __restrict__ Wb,
    float* __restrict__ out) {
    __shared__ unsigned short As[128][40];
    __shared__ unsigned short Bs[128][40];
    int tid = threadIdx.x;
    int w = tid >> 6, l = tid & 63;
    int lr = l & 15, lg = l >> 4;
    int wm = w >> 1, wn = w & 1;
    int m0 = blockIdx.x * 128, n0 = blockIdx.y * 128;

    f32x4 acc[4][4];
    #pragma unroll
    for (int i = 0; i < 4; ++i)
        #pragma unroll
        for (int j = 0; j < 4; ++j) acc[i][j] = (f32x4){0.f, 0.f, 0.f, 0.f};

    for (int k0 = 0; k0 < DM; k0 += 32) {
        __syncthreads();
        #pragma unroll
        for (int rep = 0; rep < 2; ++rep) {
            int e = rep * 256 + tid;
            int r = e >> 2, qd = e & 3;
            *(uint4*)(&As[r][qd * 8]) = *(const uint4*)(X + (size_t)(m0 + r) * DM + k0 + qd * 8);
            *(uint4*)(&Bs[r][qd * 8]) = *(const uint4*)(Wb + (size_t)(n0 + r) * DM + k0 + qd * 8);
        }
        __syncthreads();
        bf16x8 af[4], bfr[4];
        #pragma unroll
        for (int i = 0; i < 4; ++i) {
            af[i] = *(const bf16x8*)(&As[wm * 64 + i * 16 + lr][lg * 8]);
            bfr[i] = *(const bf16x8*)(&Bs[wn * 64 + i * 16 + lr][lg * 8]);
        }
        #pragma unroll
        for (int i = 0; i < 4; ++i)
            #pragma unroll
            for (int j = 0; j < 4; ++j)
                acc[i][j] = mfma16(af[i], bfr[j], acc[i][j]);
    }
    #pragma unroll
    for (int i = 0; i < 4; ++i) {
        #pragma unroll
        for (int j = 0; j < 4; ++j) {
            #pragma unroll
            for (int r = 0; r < 4; ++r) {
                int row = m0 + wm * 64 + i * 16 + lg * 4 + r;
                int col = n0 + wn * 64 + j * 16 + lr;
                out[(size_t)row * DM + col] = acc[i][j][r];
            }
        }
    }
}

extern "C" void kernel_launch(void* const* d_in, const int* in_sizes, int n_in,
                              void* d_out, int out_size, void* d_ws, size_t ws_size,
                              hipStream_t stream) {
    const float* q = (const float*)d_in[0];
    const float* k = (const float*)d_in[1];
    const float* v = (const float*)d_in[2];
    // d_in[3] = attention_mask (causal, computed from indices instead)
    const int* pos_ids = (const int*)d_in[4];
    const float* qw = (const float*)d_in[5];
    const float* kw = (const float*)d_in[6];
    const float* wout = (const float*)d_in[7];
    float* out = (float*)d_out;

    char* ws = (char*)d_ws;
    float* cosT = (float*)(ws + 0x000000);          // 512 KB
    float* sinT = (float*)(ws + 0x080000);          // 512 KB
    unsigned short* Qb = (unsigned short*)(ws + 0x100000);   // 8 MB
    unsigned short* Kb = (unsigned short*)(ws + 0x900000);   // 2 MB
    unsigned short* Vt = (unsigned short*)(ws + 0xB00000);   // 2 MB
    unsigned short* Wb = (unsigned short*)(ws + 0xD00000);   // 8 MB
    unsigned short* Xo = (unsigned short*)(ws + 0x1500000);  // 8 MB

    rope_tab<<<T_SEQ, 64, 0, stream>>>(pos_ids, cosT, sinT);
    qk_prep<<<T_SEQ, 256, 0, stream>>>(q, k, qw, kw, cosT, sinT, Qb, Kb);
    v_prep<<<dim3(T_SEQ / 64, KVD / 64), 256, 0, stream>>>(v, Vt);
    w_prep<<<(DM * DM) / (256 * 4), 256, 0, stream>>>(wout, Wb);
    attn_fwd<<<dim3(T_SEQ / 64, NH), 256, 0, stream>>>(Qb, Kb, Vt, Xo);
    outproj<<<dim3(DM / 128, DM / 128), 256, 0, stream>>>(Xo, Wb, out);
}

// Round 2
// 210.573 us; speedup vs baseline: 1.6548x; 1.6548x over previous
//
#include <hip/hip_runtime.h>
#include <hip/hip_bf16.h>
#include <math.h>

#define T_SEQ 2048
#define NH 16
#define KVH 4
#define HD 128
#define DM 2048
#define KVD 512

typedef short bf16x8 __attribute__((ext_vector_type(8)));
typedef float f32x4 __attribute__((ext_vector_type(4)));
typedef float f32x16 __attribute__((ext_vector_type(16)));
typedef unsigned int uint2v __attribute__((ext_vector_type(2)));

static __device__ __forceinline__ unsigned short f2bf(float f) {
    unsigned int x = __float_as_uint(f);
    x += 0x7fff + ((x >> 16) & 1);   // round-to-nearest-even
    return (unsigned short)(x >> 16);
}

static __device__ __forceinline__ unsigned int cvtpk(float lo, float hi) {
    unsigned int r;
    asm("v_cvt_pk_bf16_f32 %0, %1, %2" : "=v"(r) : "v"(lo), "v"(hi));
    return r;
}

static __device__ __forceinline__ f32x4 mfma16(bf16x8 a, bf16x8 b, f32x4 c) {
    return __builtin_amdgcn_mfma_f32_16x16x32_bf16(a, b, c, 0, 0, 0);
}
static __device__ __forceinline__ f32x16 mfma32(bf16x8 a, bf16x8 b, f32x16 c) {
    return __builtin_amdgcn_mfma_f32_32x32x16_bf16(a, b, c, 0, 0, 0);
}

// ---------------- kernel 1: RoPE cos/sin table [T][64] ----------------
__global__ void rope_tab(const int* __restrict__ pos_ids,
                         float* __restrict__ cosT, float* __restrict__ sinT) {
    int t = blockIdx.x;
    int i = threadIdx.x;  // 0..63
    float pos = (float)pos_ids[t];
    float inv = powf(10000.0f, -(float)i * (1.0f / 64.0f));
    float a = pos * inv;
    cosT[t * 64 + i] = cosf(a);
    sinT[t * 64 + i] = sinf(a);
}

// ---------------- kernel 2: RMSNorm + RoPE for q,k -> bf16 head-major ----------------
__global__ __launch_bounds__(256) void qk_prep(
    const float* __restrict__ q, const float* __restrict__ k,
    const float* __restrict__ qw, const float* __restrict__ kw,
    const float* __restrict__ cosT, const float* __restrict__ sinT,
    unsigned short* __restrict__ Qb, unsigned short* __restrict__ Kb) {
    __shared__ float qr[DM];
    __shared__ float kr[KVD];
    __shared__ float redq[4], redk[4];
    int t = blockIdx.x, tid = threadIdx.x;

    float qs = 0.f, ks = 0.f;
    {
        const float* qp = q + (size_t)t * DM + tid * 8;
        float4 v0 = *(const float4*)(qp);
        float4 v1 = *(const float4*)(qp + 4);
        float* dst = qr + tid * 8;
        dst[0] = v0.x; dst[1] = v0.y; dst[2] = v0.z; dst[3] = v0.w;
        dst[4] = v1.x; dst[5] = v1.y; dst[6] = v1.z; dst[7] = v1.w;
        qs = v0.x * v0.x + v0.y * v0.y + v0.z * v0.z + v0.w * v0.w +
             v1.x * v1.x + v1.y * v1.y + v1.z * v1.z + v1.w * v1.w;
        float2 kv = *(const float2*)(k + (size_t)t * KVD + tid * 2);
        kr[tid * 2] = kv.x; kr[tid * 2 + 1] = kv.y;
        ks = kv.x * kv.x + kv.y * kv.y;
    }
    for (int off = 32; off; off >>= 1) {
        qs += __shfl_down(qs, off);
        ks += __shfl_down(ks, off);
    }
    if ((tid & 63) == 0) { redq[tid >> 6] = qs; redk[tid >> 6] = ks; }
    __syncthreads();
    float qinv = rsqrtf((redq[0] + redq[1] + redq[2] + redq[3]) * (1.0f / DM) + 1e-5f);
    float kinv = rsqrtf((redk[0] + redk[1] + redk[2] + redk[3]) * (1.0f / KVD) + 1e-5f);

    {
        int base = tid * 8;
        int h = base >> 7;
        int d = base & 127;
        bool lo = d < 64;
        int i0 = d & 63;
        int pb = lo ? base + 64 : base - 64;
        #pragma unroll
        for (int j = 0; j < 8; ++j) {
            float xv = qr[base + j] * qinv * qw[base + j];
            float pv = qr[pb + j] * qinv * qw[pb + j];
            float c = cosT[t * 64 + i0 + j];
            float s = sinT[t * 64 + i0 + j];
            float o = lo ? (xv * c - pv * s) : (xv * c + pv * s);
            Qb[((size_t)h * T_SEQ + t) * HD + d + j] = f2bf(o);
        }
    }
    {
        int base = tid * 2;
        int h = base >> 7;
        int d = base & 127;
        bool lo = d < 64;
        int i0 = d & 63;
        int pb = lo ? base + 64 : base - 64;
        #pragma unroll
        for (int j = 0; j < 2; ++j) {
            float xv = kr[base + j] * kinv * kw[base + j];
            float pv = kr[pb + j] * kinv * kw[pb + j];
            float c = cosT[t * 64 + i0 + j];
            float s = sinT[t * 64 + i0 + j];
            float o = lo ? (xv * c - pv * s) : (xv * c + pv * s);
            Kb[((size_t)h * T_SEQ + t) * HD + d + j] = f2bf(o);
        }
    }
}

// ---------------- kernel 3: V -> bf16 transposed [KVH][128][T] ----------------
__global__ __launch_bounds__(256) void v_prep(const float* __restrict__ v,
                                              unsigned short* __restrict__ Vt) {
    __shared__ unsigned short tile[64][72];
    int tb = blockIdx.x;
    int cb = blockIdx.y;
    int tid = threadIdx.x;
    #pragma unroll 4
    for (int rep = 0; rep < 16; ++rep) {
        int e = rep * 256 + tid;
        int r = e >> 6;
        int c = e & 63;
        tile[c][r] = f2bf(v[(size_t)(tb * 64 + r) * KVD + cb * 64 + c]);
    }
    __syncthreads();
    #pragma unroll 4
    for (int rep = 0; rep < 16; ++rep) {
        int e = rep * 256 + tid;
        int cc = e >> 6;
        int tt = e & 63;
        Vt[(size_t)(cb * 64 + cc) * T_SEQ + tb * 64 + tt] = tile[cc][tt];
    }
}

// ---------------- kernel 4: w_out f32 -> bf16 ----------------
__global__ __launch_bounds__(256) void w_prep(const float* __restrict__ w,
                                              unsigned short* __restrict__ Wb) {
    size_t idx = ((size_t)blockIdx.x * 256 + threadIdx.x) * 4;
    float4 f = *(const float4*)(w + idx);
    ushort4 o;
    o.x = f2bf(f.x); o.y = f2bf(f.y); o.z = f2bf(f.z); o.w = f2bf(f.w);
    *(ushort4*)(Wb + idx) = o;
}

// ---------------- kernel 5: flash attention, swapped-QK^T 32x32 ----------------
// Each wave owns 32 q-rows; lane owns one q-column of S^T (lanes l, l+32 pair on k).
// No LDS / no barriers in the main loop. O^T accumulated; LDS-transposed epilogue.
template <bool MASKED>
static __device__ __forceinline__ void attn_tile(
    int kb, int qglob, int lq, int hi,
    const unsigned short* __restrict__ Kh,
    const unsigned short* __restrict__ Vh,
    const bf16x8* qf, f32x16* oacc,
    float& m, float& sden) {
    f32x16 s;
    #pragma unroll
    for (int r = 0; r < 16; ++r) s[r] = 0.f;
    #pragma unroll
    for (int sl = 0; sl < 8; ++sl) {
        bf16x8 kf = *(const bf16x8*)(Kh + (size_t)(kb + lq) * HD + sl * 16 + hi * 8);
        s = mfma32(kf, qf[sl], s);   // S^T[k][q]
    }
    const float scale = 0.08838834764831845f;  // 1/sqrt(128)
    float p[16];
    float tmax = -3.0e38f;
    #pragma unroll
    for (int r = 0; r < 16; ++r) {
        float val = s[r] * scale;
        if (MASKED) {
            int krow = kb + (r & 3) + 8 * (r >> 2) + 4 * hi;
            val = (krow <= qglob) ? val : -10000.0f;
        }
        p[r] = val;
        tmax = fmaxf(tmax, val);
    }
    tmax = fmaxf(tmax, __shfl_xor(tmax, 32));
    float ls = 0.f;
    if (__ballot(tmax > m)) {           // wave-uniform: rescale path
        float mn = fmaxf(m, tmax);
        float al = __expf(m - mn);
        m = mn;
        #pragma unroll
        for (int r = 0; r < 16; ++r) { p[r] = __expf(p[r] - mn); ls += p[r]; }
        ls += __shfl_xor(ls, 32);
        sden = sden * al + ls;
        #pragma unroll
        for (int db = 0; db < 4; ++db)
            #pragma unroll
            for (int r = 0; r < 16; ++r) oacc[db][r] *= al;
    } else {                             // T13 defer-max: no rescale needed
        #pragma unroll
        for (int r = 0; r < 16; ++r) { p[r] = __expf(p[r] - m); ls += p[r]; }
        ls += __shfl_xor(ls, 32);
        sden = sden + ls;
    }
    // P^T -> bf16 B-fragments via cvt_pk + permlane32_swap (T12)
    #pragma unroll
    for (int half = 0; half < 2; ++half) {
        unsigned int a0 = cvtpk(p[half * 8 + 0], p[half * 8 + 1]);
        unsigned int a1 = cvtpk(p[half * 8 + 2], p[half * 8 + 3]);
        unsigned int b0 = cvtpk(p[half * 8 + 4], p[half * 8 + 5]);
        unsigned int b1 = cvtpk(p[half * 8 + 6], p[half * 8 + 7]);
        uint2v w0 = __builtin_amdgcn_permlane32_swap(a0, b0, false, false);
        uint2v w1 = __builtin_amdgcn_permlane32_swap(a1, b1, false, false);
        union { unsigned int u[4]; bf16x8 v; } pc;
        pc.u[0] = w0[0]; pc.u[1] = w1[0]; pc.u[2] = w0[1]; pc.u[3] = w1[1];
        bf16x8 pf = pc.v;
        #pragma unroll
        for (int db = 0; db < 4; ++db) {
            bf16x8 vf = *(const bf16x8*)(Vh + (size_t)(db * 32 + lq) * T_SEQ + kb + half * 16 + hi * 8);
            oacc[db] = mfma32(vf, pf, oacc[db]);   // O^T[d][q]
        }
    }
}

__global__ __launch_bounds__(128, 2) void attn_fwd2(
    const unsigned short* __restrict__ Qb, const unsigned short* __restrict__ Kb,
    const unsigned short* __restrict__ Vt, unsigned short* __restrict__ Xo) {
    int qb = (int)gridDim.x - 1 - (int)blockIdx.x;  // heavy blocks first
    int h = blockIdx.y;
    int kh = h >> 2;
    int tid = threadIdx.x;
    int w = tid >> 6, l = tid & 63;
    int lq = l & 31, hi = l >> 5;
    int q0 = qb * 64 + w * 32;
    int qglob = q0 + lq;

    const unsigned short* Qh = Qb + (size_t)h * T_SEQ * HD;
    const unsigned short* Kh = Kb + (size_t)kh * T_SEQ * HD;
    const unsigned short* Vh = Vt + (size_t)kh * HD * T_SEQ;

    bf16x8 qf[8];  // Q row in registers, B-operand layout
    #pragma unroll
    for (int sl = 0; sl < 8; ++sl)
        qf[sl] = *(const bf16x8*)(Qh + (size_t)qglob * HD + sl * 16 + hi * 8);

    f32x16 oacc[4];
    #pragma unroll
    for (int db = 0; db < 4; ++db)
        #pragma unroll
        for (int r = 0; r < 16; ++r) oacc[db][r] = 0.f;

    float m = -1e30f, sden = 0.f;
    int nkt = qb * 2 + w + 1;
    for (int kt = 0; kt < nkt - 1; ++kt)
        attn_tile<false>(kt * 32, qglob, lq, hi, Kh, Vh, qf, oacc, m, sden);
    attn_tile<true>((nkt - 1) * 32, qglob, lq, hi, Kh, Vh, qf, oacc, m, sden);

    // epilogue: O^T -> LDS -> coalesced row-major bf16 store
    __shared__ __align__(16) unsigned short ot[2][32][136];  // 272B rows: 16B-aligned
    float invs = 1.0f / sden;
    #pragma unroll
    for (int db = 0; db < 4; ++db) {
        #pragma unroll
        for (int g = 0; g < 4; ++g) {
            ushort4 pk;
            pk.x = f2bf(oacc[db][g * 4 + 0] * invs);
            pk.y = f2bf(oacc[db][g * 4 + 1] * invs);
            pk.z = f2bf(oacc[db][g * 4 + 2] * invs);
            pk.w = f2bf(oacc[db][g * 4 + 3] * invs);
            *(ushort4*)(&ot[w][lq][db * 32 + 8 * g + 4 * hi]) = pk;
        }
    }
    __syncthreads();
    #pragma unroll
    for (int rep = 0; rep < 8; ++rep) {
        int row = rep * 4 + (l >> 4);
        int d0 = (l & 15) * 8;
        bf16x8 vv = *(const bf16x8*)(&ot[w][row][d0]);
        *(bf16x8*)(Xo + (size_t)(q0 + row) * DM + h * HD + d0) = vv;
    }
}

// ---------------- kernel 6: out = X(bf16) @ W^T(bf16) -> f32 ----------------
__global__ __launch_bounds__(256) void outproj(
    const unsigned short* __restrict__ X, const unsigned short* __restrict__ Wb,
    float* __restrict__ out) {
    __shared__ unsigned short As[128][40];
    __shared__ unsigned short Bs[128][40];
    int tid = threadIdx.x;
    int w = tid >> 6, l = tid & 63;
    int lr = l & 15, lg = l >> 4;
    int wm = w >> 1, wn = w & 1;
    int m0 = blockIdx.x * 128, n0 = blockIdx.y * 128;

    f32x4 acc[4][4];
    #pragma unroll
    for (int i = 0; i < 4; ++i)
        #pragma unroll
        for (int j = 0; j < 4; ++j) acc[i][j] = (f32x4){0.f, 0.f, 0.f, 0.f};

    for (int k0 = 0; k0 < DM; k0 += 32) {
        __syncthreads();
        #pragma unroll
        for (int rep = 0; rep < 2; ++rep) {
            int e = rep * 256 + tid;
            int r = e >> 2, qd = e & 3;
            *(uint4*)(&As[r][qd * 8]) = *(const uint4*)(X + (size_t)(m0 + r) * DM + k0 + qd * 8);
            *(uint4*)(&Bs[r][qd * 8]) = *(const uint4*)(Wb + (size_t)(n0 + r) * DM + k0 + qd * 8);
        }
        __syncthreads();
        bf16x8 af[4], bfr[4];
        #pragma unroll
        for (int i = 0; i < 4; ++i) {
            af[i] = *(const bf16x8*)(&As[wm * 64 + i * 16 + lr][lg * 8]);
            bfr[i] = *(const bf16x8*)(&Bs[wn * 64 + i * 16 + lr][lg * 8]);
        }
        #pragma unroll
        for (int i = 0; i < 4; ++i)
            #pragma unroll
            for (int j = 0; j < 4; ++j)
                acc[i][j] = mfma16(af[i], bfr[j], acc[i][j]);
    }
    #pragma unroll
    for (int i = 0; i < 4; ++i) {
        #pragma unroll
        for (int j = 0; j < 4; ++j) {
            #pragma unroll
            for (int r = 0; r < 4; ++r) {
                int row = m0 + wm * 64 + i * 16 + lg * 4 + r;
                int col = n0 + wn * 64 + j * 16 + lr;
                out[(size_t)row * DM + col] = acc[i][j][r];
            }
        }
    }
}

extern "C" void kernel_launch(void* const* d_in, const int* in_sizes, int n_in,
                              void* d_out, int out_size, void* d_ws, size_t ws_size,
                              hipStream_t stream) {
    const float* q = (const float*)d_in[0];
    const float* k = (const float*)d_in[1];
    const float* v = (const float*)d_in[2];
    const int* pos_ids = (const int*)d_in[4];
    const float* qw = (const float*)d_in[5];
    const float* kw = (const float*)d_in[6];
    const float* wout = (const float*)d_in[7];
    float* out = (float*)d_out;

    char* ws = (char*)d_ws;
    float* cosT = (float*)(ws + 0x000000);
    float* sinT = (float*)(ws + 0x080000);
    unsigned short* Qb = (unsigned short*)(ws + 0x100000);
    unsigned short* Kb = (unsigned short*)(ws + 0x900000);
    unsigned short* Vt = (unsigned short*)(ws + 0xB00000);
    unsigned short* Wb = (unsigned short*)(ws + 0xD00000);
    unsigned short* Xo = (unsigned short*)(ws + 0x1500000);

    rope_tab<<<T_SEQ, 64, 0, stream>>>(pos_ids, cosT, sinT);
    qk_prep<<<T_SEQ, 256, 0, stream>>>(q, k, qw, kw, cosT, sinT, Qb, Kb);
    v_prep<<<dim3(T_SEQ / 64, KVD / 64), 256, 0, stream>>>(v, Vt);
    w_prep<<<(DM * DM) / (256 * 4), 256, 0, stream>>>(wout, Wb);
    attn_fwd2<<<dim3(T_SEQ / 64, NH), 128, 0, stream>>>(Qb, Kb, Vt, Xo);
    outproj<<<dim3(DM / 128, DM / 128), 256, 0, stream>>>(Xo, Wb, out);
}